// Round 20
// baseline (107.754 us; speedup 1.0000x reference)
//
#include <hip/hip_runtime.h>
#include <math.h>

// CIN (xDeepFM) — fp16 MFMA, scale FOLDED INTO B (z-fragments) with MFMA C-in
// chaining: NO VALU instruction reads an MFMA result in the hot loop (kills
// the XDL-write->VALU-read hazard wait-states). 2 batches/block, register-
// direct A with pointer-bump prefetch, fused final epilogue. 4 dispatches.
// y[b,o,d] = bias[o] + sum_{f,h} W[o,fH+h] * (x[b,f,d]*h[b,h,d])
//   z-frag  = fp16(h) * fp16(x-scale)  (pk_mul, fp16)
//   Y       = mfma(W16, z, Y)          (f32 accumulate in MFMA C)
// out[b] = sigmoid( relu(concat outs) . Wout + bout )  (fused into layer 3)
// B=512, F=32, D=64, O=128; H0=32 (h=x), H1=H2=128; NPASS=H/32.

typedef __attribute__((ext_vector_type(8))) _Float16 f16x8;
typedef __attribute__((ext_vector_type(4))) _Float16 f16x4;
typedef __attribute__((ext_vector_type(4))) float f32x4;
typedef __attribute__((ext_vector_type(4))) unsigned short u16x4;

__device__ __forceinline__ unsigned short f2h(float f) {
  union { _Float16 h; unsigned short u; } c; c.h = (_Float16)f; return c.u;
}

__device__ __forceinline__ void gll16(const void* g, void* l) {
  __builtin_amdgcn_global_load_lds(
      (const __attribute__((address_space(1))) unsigned int*)g,
      (__attribute__((address_space(3))) unsigned int*)l, 16, 0, 0);
}

// ---- single merged pre-pass: repack all three W into fp16 fragment-linear
// images, chunk-sequential in iteration order (chunk c = pass*32+f at unit c*512).
// blocks [0,64) -> W0, [64,320) -> W1, [320,576) -> W2.
// element: W[o = mt*16+(l&15)][kcol = f*H + pass*32 + ((l>>4)&3)*8 + j], j=0..7
__global__ void repack_w_all(const float* __restrict__ W0q, const float* __restrict__ W1q,
                             const float* __restrict__ W2q,
                             unsigned short* __restrict__ D0, unsigned short* __restrict__ D1,
                             unsigned short* __restrict__ D2)
{
  const int blk = blockIdx.x;
  const float* W; unsigned short* dst; int H, t;
  if (blk < 64)       { W = W0q; dst = D0; H = 32;  t = blk * 256 + threadIdx.x; }
  else if (blk < 320) { W = W1q; dst = D1; H = 128; t = (blk - 64) * 256 + threadIdx.x; }
  else                { W = W2q; dst = D2; H = 128; t = (blk - 320) * 256 + threadIdx.x; }
  const int K = 32 * H;
  const int idx = t & 511;
  const int c   = t >> 9;
  const int pass = c >> 5, f = c & 31;
  const int mt = idx >> 6, l = idx & 63;
  const int o = mt * 16 + (l & 15);
  const int kcol = f * H + pass * 32 + ((l >> 4) & 3) * 8;
  const float* s = W + (size_t)o * K + kcol;
  u16x4 a, bq;
#pragma unroll
  for (int j = 0; j < 4; ++j) {
    a[j]  = f2h(s[j]);
    bq[j] = f2h(s[4 + j]);
  }
  *(u16x4*)(dst + (size_t)t * 8)     = a;
  *(u16x4*)(dst + (size_t)t * 8 + 4) = bq;
}

// one body: 2 fp16x4 scale reads, build 8 z-fragments (pk_mul, no MFMA-result
// reads), 8 C-chained MFMAs, ONE pointer-bump A prefetch.
#define BODY(SPOFF, Ac, Ad, Ap)                                                 \
  {                                                                             \
    const f16x4 sv0 = *(const f16x4*)(xp0 + (SPOFF));                           \
    const f16x4 sv1 = *(const f16x4*)(xp1 + (SPOFF));                           \
    const f16x8 z00 = Bh0[0] * sv0[0];                                          \
    const f16x8 z01 = Bh0[1] * sv0[1];                                          \
    const f16x8 z02 = Bh0[2] * sv0[2];                                          \
    const f16x8 z03 = Bh0[3] * sv0[3];                                          \
    const f16x8 z10 = Bh1[0] * sv1[0];                                          \
    const f16x8 z11 = Bh1[1] * sv1[1];                                          \
    const f16x8 z12 = Bh1[2] * sv1[2];                                          \
    const f16x8 z13 = Bh1[3] * sv1[3];                                          \
    Y0[0] = __builtin_amdgcn_mfma_f32_16x16x32_f16(Ac, z00, Y0[0], 0, 0, 0);    \
    Y1[0] = __builtin_amdgcn_mfma_f32_16x16x32_f16(Ac, z10, Y1[0], 0, 0, 0);    \
    Y0[1] = __builtin_amdgcn_mfma_f32_16x16x32_f16(Ac, z01, Y0[1], 0, 0, 0);    \
    Y1[1] = __builtin_amdgcn_mfma_f32_16x16x32_f16(Ac, z11, Y1[1], 0, 0, 0);    \
    Y0[2] = __builtin_amdgcn_mfma_f32_16x16x32_f16(Ac, z02, Y0[2], 0, 0, 0);    \
    Y1[2] = __builtin_amdgcn_mfma_f32_16x16x32_f16(Ac, z12, Y1[2], 0, 0, 0);    \
    Y0[3] = __builtin_amdgcn_mfma_f32_16x16x32_f16(Ac, z03, Y0[3], 0, 0, 0);    \
    Y1[3] = __builtin_amdgcn_mfma_f32_16x16x32_f16(Ac, z13, Y1[3], 0, 0, 0);    \
    Ad = Ap[0];                                                                 \
    Ap += 1024;                                                                 \
  }

// ---- main layer kernel ----
// grid 256 x 512 threads; block handles b0=2*blk, b0+1; wave w owns o in [16w,16w+16).
// LDS: [0,8K) x[b0]; [8K,16K) x[b0+1]; [16K,20K) xt16_0; [20K,24K) xt16_1
//      xt16[f][li][q] = fp16(x[f][q*16+li]) (per-body scales as one b64 read).
template<int H, int NPASS, bool FIRST, bool STORE_H, bool FINAL>
__global__ __launch_bounds__(512, 2) void cin_mfma_layer(
    const unsigned short* __restrict__ Wimg,   // fp16 plane, fragment-linear (+2 chunk pad)
    const float* __restrict__ x,               // (B,32,64) fp32
    const unsigned short* __restrict__ hTin,   // fp16 hT[b][d][hrow] (null if FIRST)
    const float* __restrict__ bias,
    unsigned short* __restrict__ hTout,        // fp16 hT[b][d][orow]
    float* __restrict__ outs, int col_off,     // (B,256) cols 0..255 (layers 0,1)
    const float* __restrict__ Wout,            // (384) — FINAL only
    const float* __restrict__ bout,            // (1)   — FINAL only
    float* __restrict__ out)                   // (B)   — FINAL only
{
  __shared__ char lds[24576];
  const int tid = threadIdx.x;
  const int w = tid >> 6, l = tid & 63, g = l >> 4, li = l & 15;
  const int b0 = blockIdx.x * 2;
  const float* lx0 = (const float*)lds;
  const float* lx1 = (const float*)(lds + 8192);
  const _Float16* xt0 = (const _Float16*)(lds + 16384);
  const _Float16* xt1 = (const _Float16*)(lds + 20480);

  // prologue: stage x[b0], x[b0+1] (2 x 8KB, lane-linear)
  gll16(x + (size_t)b0 * 2048 + tid * 4,       lds + w * 1024);
  gll16(x + (size_t)(b0 + 1) * 2048 + tid * 4, lds + 8192 + w * 1024);

  f32x4 Y0[4], Y1[4];
#pragma unroll
  for (int nt = 0; nt < 4; ++nt) {
    Y0[nt] = (f32x4){0.f, 0.f, 0.f, 0.f};
    Y1[nt] = (f32x4){0.f, 0.f, 0.f, 0.f};
  }
  f16x8 Bh0[4], Bh1[4];

  asm volatile("s_waitcnt vmcnt(0)" ::: "memory");
  __builtin_amdgcn_s_barrier();

  // build fp16 transposed scale tiles for both batches (512 thr = 32f x 16li)
  {
    const int tf = tid >> 4, tl = tid & 15;
    f16x4 v0, v1;
#pragma unroll
    for (int q = 0; q < 4; ++q) {
      v0[q] = (_Float16)lx0[tf * 64 + q * 16 + tl];
      v1[q] = (_Float16)lx1[tf * 64 + q * 16 + tl];
    }
    *(f16x4*)(lds + 16384 + (tf * 16 + tl) * 8) = v0;
    *(f16x4*)(lds + 20480 + (tf * 16 + tl) * 8) = v1;
  }
  __builtin_amdgcn_s_barrier();

  if constexpr (FIRST) {
    // build fp16 B-fragments from raw x (h == x; NPASS==1), both batches
#pragma unroll
    for (int nt = 0; nt < 4; ++nt) {
      union { f16x8 v; _Float16 u[8]; } t0, t1;
#pragma unroll
      for (int j = 0; j < 8; ++j) {
        t0.u[j] = (_Float16)lx0[(g * 8 + j) * 64 + nt * 16 + li];
        t1.u[j] = (_Float16)lx1[(g * 8 + j) * 64 + nt * 16 + li];
      }
      Bh0[nt] = t0.v; Bh1[nt] = t1.v;
    }
  }

  // wave's A-fragment base: 16B unit (w*64 + l); chunk stride 512 units
  const f16x8* Abase = (const f16x8*)Wimg + (w * 64 + l);
  f16x8 Aa = Abase[0];
  f16x8 Ab = Abase[512];
  const f16x8* ApA = Abase + 1024;
  const f16x8* ApB = Abase + 1536;

  for (int pass = 0; pass < NPASS; ++pass) {
    if constexpr (!FIRST) {
      // B-fragments for this pass, both batches (reused across all 32 f)
#pragma unroll
      for (int nt = 0; nt < 4; ++nt) {
        const size_t co = (size_t)(nt * 16 + li) * 128 + pass * 32 + g * 8;
        Bh0[nt] = *(const f16x8*)(hTin + (size_t)b0 * 8192 + co);
        Bh1[nt] = *(const f16x8*)(hTin + (size_t)(b0 + 1) * 8192 + co);
      }
    }
    const _Float16* xp0 = xt0 + li * 4;
    const _Float16* xp1 = xt1 + li * 4;
#pragma unroll 1
    for (int fo = 0; fo < 32; fo += 2) {
      BODY(0,  Aa, Aa, ApA)
      BODY(64, Ab, Ab, ApB)
      xp0 += 128;
      xp1 += 128;
    }
  }

  // ---- epilogue: bias, fp16 hT stores, row-sums (both batches) ----
  const f32x4 bv = *(const f32x4*)(bias + w * 16 + g * 4);
#pragma unroll
  for (int nt = 0; nt < 4; ++nt) { Y0[nt] += bv; Y1[nt] += bv; }

  if constexpr (STORE_H) {
#pragma unroll
    for (int nt = 0; nt < 4; ++nt) {
      const int d = nt * 16 + li;
      u16x4 p0, p1;
#pragma unroll
      for (int j = 0; j < 4; ++j) { p0[j] = f2h(Y0[nt][j]); p1[j] = f2h(Y1[nt][j]); }
      const size_t co = (size_t)d * 128 + w * 16 + g * 4;
      *(u16x4*)(hTout + (size_t)b0 * 8192 + co)       = p0;
      *(u16x4*)(hTout + (size_t)(b0 + 1) * 8192 + co) = p1;
    }
  }

  f32x4 s0 = Y0[0] + Y0[1] + Y0[2] + Y0[3];
  f32x4 s1 = Y1[0] + Y1[1] + Y1[2] + Y1[3];
#pragma unroll
  for (int m = 1; m < 16; m <<= 1) {
    s0.x += __shfl_xor(s0.x, m, 16); s0.y += __shfl_xor(s0.y, m, 16);
    s0.z += __shfl_xor(s0.z, m, 16); s0.w += __shfl_xor(s0.w, m, 16);
    s1.x += __shfl_xor(s1.x, m, 16); s1.y += __shfl_xor(s1.y, m, 16);
    s1.z += __shfl_xor(s1.z, m, 16); s1.w += __shfl_xor(s1.w, m, 16);
  }

  if constexpr (FINAL) {
    // fused: out[b] = sigmoid( relu(outs[b,0:256]).Wout[0:256]
    //                        + relu(own 128 sums).Wout[256:384] + bout ), both b
    __builtin_amdgcn_s_barrier();            // all waves done reading lx/xt
    float* shs = (float*)lds;
    if (li == 0) {
      *(f32x4*)(shs + w * 16 + g * 4)       = s0;
      *(f32x4*)(shs + 128 + w * 16 + g * 4) = s1;
    }
    __builtin_amdgcn_s_barrier();
    if (w < 2) {
      const int bb = b0 + w;
      const float* sh = shs + w * 128;
      float acc;
      {
        float v0 = sh[l];      v0 = v0 > 0.f ? v0 : 0.f;
        float v1 = sh[l + 64]; v1 = v1 > 0.f ? v1 : 0.f;
        acc = v0 * Wout[256 + l] + v1 * Wout[320 + l];
      }
#pragma unroll
      for (int q = 0; q < 4; ++q) {
        float v = outs[(size_t)bb * 256 + q * 64 + l];
        v = v > 0.f ? v : 0.f;
        acc = fmaf(v, Wout[q * 64 + l], acc);
      }
#pragma unroll
      for (int m = 32; m; m >>= 1) acc += __shfl_xor(acc, m, 64);
      if (l == 0) {
        const float t = acc + bout[0];
        out[bb] = 1.f / (1.f + expf(-t));
      }
    }
  } else {
    if (li == 0) {
      *(f32x4*)(outs + (size_t)b0 * 256 + col_off + w * 16 + g * 4)       = s0;
      *(f32x4*)(outs + (size_t)(b0 + 1) * 256 + col_off + w * 16 + g * 4) = s1;
    }
  }
}

extern "C" void kernel_launch(void* const* d_in, const int* in_sizes, int n_in,
                              void* d_out, int out_size, void* d_ws, size_t ws_size,
                              hipStream_t stream)
{
  const float* x    = (const float*)d_in[0];
  const float* W0   = (const float*)d_in[1];
  const float* b0   = (const float*)d_in[2];
  const float* W1   = (const float*)d_in[3];
  const float* b1   = (const float*)d_in[4];
  const float* W2   = (const float*)d_in[5];
  const float* b2   = (const float*)d_in[6];
  const float* Wout = (const float*)d_in[7];
  const float* bout = (const float*)d_in[8];
  float* out = (float*)d_out;

  char* ws = (char*)d_ws;
  unsigned short* hT1  = (unsigned short*)ws;                        // 8 MB (fp16)
  unsigned short* hT2  = (unsigned short*)(ws + (8 << 20));          // 8 MB
  float*          outs = (float*)        (ws + (16 << 20));          // 512 KB
  unsigned short* Wi0  = (unsigned short*)(ws + (17 << 20));                 // 256 KB + pad
  unsigned short* Wi1  = (unsigned short*)(ws + (17 << 20) + (1 << 19));     // 1 MB + pad
  unsigned short* Wi2  = (unsigned short*)(ws + (19 << 20));                 // 1 MB + pad

  repack_w_all<<<576, 256, 0, stream>>>(W0, W1, W2, Wi0, Wi1, Wi2);

  cin_mfma_layer<32,  1, true,  true,  false><<<256, 512, 0, stream>>>(
      Wi0, x, nullptr, b0, hT1, outs, 0, nullptr, nullptr, nullptr);
  cin_mfma_layer<128, 4, false, true,  false><<<256, 512, 0, stream>>>(
      Wi1, x, hT1, b1, hT2, outs, 128, nullptr, nullptr, nullptr);
  cin_mfma_layer<128, 4, false, false, true ><<<256, 512, 0, stream>>>(
      Wi2, x, hT2, b2, nullptr, outs, 0, Wout, bout, out);
}